// Round 10
// baseline (306.662 us; speedup 1.0000x reference)
//
#include <hip/hip_runtime.h>
#include <math.h>

#define NB 8
#define NN 10000
#define NE 160000
#define FD 64
#define BN (NB * NN)              // 80000
#define TOTE (NB * NE)            // 1280000
#define EPB 10000                 // edges per count chunk
#define BPG (NE / EPB)            // 16 chunks per graph
#define NPA (NB * BPG)            // 128 count blocks
#define FILLB 1000                // fill blocks: 125/graph, 5 edges/thread (5*256*125 = NE)
#define LINB 320                  // linear blocks (40 per graph)
#define WTS 68                    // padded Wt stride

// ---------- 1: LDS histogram count + per-edge local rank (128 blocks) ----------
__global__ __launch_bounds__(256) void k_count_lds(const int* __restrict__ ei,
                                                   int* __restrict__ rank,
                                                   int* __restrict__ cnt) {
    __shared__ int hist[NN];  // 40 KB
    for (int i = threadIdx.x; i < NN; i += 256) hist[i] = 0;
    __syncthreads();
    int g = blockIdx.x >> 4;
    int j = blockIdx.x & 15;
    int base = g * NE + j * EPB;
    for (int i = threadIdx.x; i < EPB; i += 256) {
        int e = base + i;
        int r = ei[2 * e];
        rank[e] = atomicAdd(&hist[r], 1);
    }
    __syncthreads();
    int* cp = cnt + (size_t)blockIdx.x * NN;
    for (int i = threadIdx.x; i < NN; i += 256) cp[i] = hist[i];
}

// ---------- 2: per-graph scan (8 blocks x 1024) ----------
// Converts cnt in-place to ABSOLUTE CSR positions per (chunk,node):
//   start2[j][i] = g*NE + node_prefix(i) + chunk_prefix(j,i)
// so fill needs a single random gather. Also writes row_start + dinv.
__global__ __launch_bounds__(1024) void k_scan_g(int* __restrict__ cnt,
                                                 int* __restrict__ row_start,
                                                 float* __restrict__ dinv) {
    __shared__ int wsums[16];
    __shared__ int carry_s;
    const int g = blockIdx.x;
    const int tid = threadIdx.x;
    const int lane = tid & 63;
    const int wv = tid >> 6;
    if (tid == 0) carry_s = 0;
    if (g == 0 && tid == 0) row_start[BN] = TOTE;
    __syncthreads();
    for (int base = 0; base < NN; base += 1024) {
        int i = base + tid;
        int d = 0;
        int* cp = cnt + ((size_t)g * BPG) * NN + i;
        if (i < NN) {
            int run = 0;
#pragma unroll
            for (int j = 0; j < BPG; j++) {
                int v = cp[(size_t)j * NN];
                cp[(size_t)j * NN] = run;     // within-node chunk prefix
                run += v;
            }
            d = run;
        }
        int x = d;
#pragma unroll
        for (int off = 1; off < 64; off <<= 1) {
            int y = __shfl_up(x, off);
            if (lane >= off) x += y;
        }
        if (lane == 63) wsums[wv] = x;
        __syncthreads();
        if (wv == 0 && lane < 16) {
            int s = wsums[lane];
#pragma unroll
            for (int off = 1; off < 16; off <<= 1) {
                int y = __shfl_up(s, off, 16);
                if (lane >= off) s += y;
            }
            wsums[lane] = s;
        }
        __syncthreads();
        int excl = carry_s + ((wv > 0) ? wsums[wv - 1] : 0) + (x - d);
        if (i < NN) {
            int abs0 = g * NE + excl;
            row_start[g * NN + i] = abs0;
            dinv[g * NN + i] = (d > 0) ? (1.0f / sqrtf((float)d)) : 0.0f;
            // fold absolute base into each chunk's entry -> start2
#pragma unroll
            for (int j = 0; j < BPG; j++) cp[(size_t)j * NN] += abs0;
        }
        __syncthreads();
        if (tid == 0) carry_s += wsums[15];
        __syncthreads();
    }
}

// ---------- 3: fill CSR col-only (blocks 0..999, 5 edges/thread) + linear1 ----------
__global__ __launch_bounds__(256) void k_fill_lin(const int* __restrict__ ei,
                                                  const int* __restrict__ rank,
                                                  const int* __restrict__ start2,
                                                  int* __restrict__ edge_col,
                                                  const float* __restrict__ x,
                                                  const float* __restrict__ W1,
                                                  const float* __restrict__ b1,
                                                  const float* __restrict__ dinv,
                                                  float* __restrict__ t1) {
    __shared__ __align__(16) float Wt[WTS * FD];
    __shared__ float bsh[FD];
    if (blockIdx.x < FILLB) {
        // ---- fill path: 5 independent edge chains per thread (ILP) ----
        int g = blockIdx.x & 7;
        int j = blockIdx.x >> 3;                 // 0..124
        int base = j * 1280 + (int)threadIdx.x;  // within-graph edge idx
        int2 rc[5];
        int rk[5];
        int idxs[5];
#pragma unroll
        for (int u = 0; u < 5; u++) {
            int idx = base + u * 256;
            idxs[u] = idx;
            int e = g * NE + idx;
            rc[u] = ((const int2*)ei)[e];        // {row, col} local
            rk[u] = rank[g * NE + idx];
        }
        int pos[5];
#pragma unroll
        for (int u = 0; u < 5; u++) {
            int jj = idxs[u] / EPB;              // chunk id
            pos[u] = start2[((size_t)(g * BPG + jj)) * NN + rc[u].x] + rk[u];
        }
#pragma unroll
        for (int u = 0; u < 5; u++)
            edge_col[pos[u]] = g * NN + rc[u].y;
    } else {
        // ---- linear1: t1 = dinv[n] * (x @ W1^T + b1) ----
        for (int idx = threadIdx.x; idx < FD * FD; idx += 256) {
            int j = idx >> 6, k = idx & 63;
            Wt[k * WTS + j] = W1[idx];
        }
        if (threadIdx.x < FD) bsh[threadIdx.x] = b1[threadIdx.x];
        __syncthreads();

        int b = blockIdx.x - FILLB;
        int g = b & 7;
        int i = b >> 3;
        int nl = i * 256 + (int)threadIdx.x;
        if (nl >= NN) return;
        int n = g * NN + nl;

        float acc[FD];
#pragma unroll
        for (int j = 0; j < FD; j++) acc[j] = bsh[j];

        const float4* hp = (const float4*)(x + (size_t)n * FD);
#pragma unroll
        for (int k4 = 0; k4 < 16; k4++) {
            float4 hv = hp[k4];
            float hk[4] = {hv.x, hv.y, hv.z, hv.w};
#pragma unroll
            for (int kk = 0; kk < 4; kk++) {
                const float4* wr = (const float4*)(&Wt[(k4 * 4 + kk) * WTS]);
                float h = hk[kk];
#pragma unroll
                for (int j4 = 0; j4 < 16; j4++) {
                    float4 w = wr[j4];
                    acc[4 * j4 + 0] += h * w.x;
                    acc[4 * j4 + 1] += h * w.y;
                    acc[4 * j4 + 2] += h * w.z;
                    acc[4 * j4 + 3] += h * w.w;
                }
            }
        }
        float dn = dinv[n];
        float4* op = (float4*)(t1 + (size_t)n * FD);
#pragma unroll
        for (int j4 = 0; j4 < 16; j4++)
            op[j4] = make_float4(dn * acc[4 * j4], dn * acc[4 * j4 + 1],
                                 dn * acc[4 * j4 + 2], dn * acc[4 * j4 + 3]);
    }
}

// ---------- linear (layers 2,3): t[n] = dinv[n] * (relu(h[n]) @ W^T + b) ----------
__global__ __launch_bounds__(256) void k_linear(const float* __restrict__ hin,
                                                const float* __restrict__ W,
                                                const float* __restrict__ bias,
                                                const float* __restrict__ dinv,
                                                float* __restrict__ tout) {
    __shared__ __align__(16) float Wt[WTS * FD];
    __shared__ float bsh[FD];
    for (int idx = threadIdx.x; idx < FD * FD; idx += 256) {
        int j = idx >> 6, k = idx & 63;
        Wt[k * WTS + j] = W[idx];
    }
    if (threadIdx.x < FD) bsh[threadIdx.x] = bias[threadIdx.x];
    __syncthreads();

    int b = blockIdx.x;
    int g = b & 7;
    int i = b >> 3;
    int nl = i * 256 + (int)threadIdx.x;
    if (nl >= NN) return;
    int n = g * NN + nl;

    float acc[FD];
#pragma unroll
    for (int j = 0; j < FD; j++) acc[j] = bsh[j];

    const float4* hp = (const float4*)(hin + (size_t)n * FD);
#pragma unroll
    for (int k4 = 0; k4 < 16; k4++) {
        float4 hv = hp[k4];
        hv.x = fmaxf(hv.x, 0.f);
        hv.y = fmaxf(hv.y, 0.f);
        hv.z = fmaxf(hv.z, 0.f);
        hv.w = fmaxf(hv.w, 0.f);
        float hk[4] = {hv.x, hv.y, hv.z, hv.w};
#pragma unroll
        for (int kk = 0; kk < 4; kk++) {
            const float4* wr = (const float4*)(&Wt[(k4 * 4 + kk) * WTS]);
            float h = hk[kk];
#pragma unroll
            for (int j4 = 0; j4 < 16; j4++) {
                float4 w = wr[j4];
                acc[4 * j4 + 0] += h * w.x;
                acc[4 * j4 + 1] += h * w.y;
                acc[4 * j4 + 2] += h * w.z;
                acc[4 * j4 + 3] += h * w.w;
            }
        }
    }
    float dn = dinv[n];
    float4* op = (float4*)(tout + (size_t)n * FD);
#pragma unroll
    for (int j4 = 0; j4 < 16; j4++)
        op[j4] = make_float4(dn * acc[4 * j4], dn * acc[4 * j4 + 1],
                             dn * acc[4 * j4 + 2], dn * acc[4 * j4 + 3]);
}

// ---------- aggregate: out[r] = dinv[r] * sum_e t[col[e]]  (t pre-scaled by dinv) ----------
// One node per wave; coalesced superchunk metadata + shfl broadcast;
// ~290 lane-addresses/wave (TA-model floor for fp32 rows).
__global__ __launch_bounds__(256) void k_agg(const float* __restrict__ t,
                                             const int* __restrict__ row_start,
                                             const int* __restrict__ edge_col,
                                             const float* __restrict__ dinv,
                                             float* __restrict__ out) {
    int g = blockIdx.x & 7;
    int i = blockIdx.x >> 3;                          // 0..2499
    int lane = threadIdx.x & 63;
    int node = __builtin_amdgcn_readfirstlane(g * NN + i * 4 + ((int)threadIdx.x >> 6));
    int p0 = row_start[node];
    int pe = row_start[node + 1];
    float dr = dinv[node];
    int eg = lane >> 4;
    int fl = lane & 15;
    float4 acc = make_float4(0.f, 0.f, 0.f, 0.f);

    for (int sb = p0; sb < pe; sb += 64) {
        int pl = sb + lane;
        int col = (pl < pe) ? edge_col[pl] : 0;
        int cnt = pe - sb;
        if (cnt > 64) cnt = 64;
        int kmax = (cnt + 3) >> 2;
        for (int k = 0; k < kmax; k++) {
            int s = k * 4 + eg;
            int c = __shfl(col, s);
            if (s < cnt) {
                float4 tv = ((const float4*)(t + (size_t)c * FD))[fl];
                acc.x += tv.x;
                acc.y += tv.y;
                acc.z += tv.z;
                acc.w += tv.w;
            }
        }
    }
    acc.x += __shfl_down(acc.x, 32); acc.y += __shfl_down(acc.y, 32);
    acc.z += __shfl_down(acc.z, 32); acc.w += __shfl_down(acc.w, 32);
    acc.x += __shfl_down(acc.x, 16); acc.y += __shfl_down(acc.y, 16);
    acc.z += __shfl_down(acc.z, 16); acc.w += __shfl_down(acc.w, 16);
    if (lane < 16) {
        float4* op = (float4*)(out + (size_t)node * FD);
        op[fl] = make_float4(dr * acc.x, dr * acc.y, dr * acc.z, dr * acc.w);
    }
}

extern "C" void kernel_launch(void* const* d_in, const int* in_sizes, int n_in,
                              void* d_out, int out_size, void* d_ws, size_t ws_size,
                              hipStream_t stream) {
    const float* x  = (const float*)d_in[0];
    const int*   ei = (const int*)d_in[1];
    const float* W1 = (const float*)d_in[2];
    const float* b1 = (const float*)d_in[3];
    const float* W2 = (const float*)d_in[4];
    const float* b2 = (const float*)d_in[5];
    const float* W3 = (const float*)d_in[6];
    const float* b3 = (const float*)d_in[7];
    float* out = (float*)d_out;

    char* ws = (char*)d_ws;
    size_t off = 0;
    float* A        = (float*)(ws + off); off += (size_t)BN * FD * 4;     // 20.48 MB
    float* Bb       = (float*)(ws + off); off += (size_t)BN * FD * 4;     // 20.48 MB
    int*   edge_col = (int*)(ws + off);   off += (size_t)TOTE * 4;        // 5.12 MB
    int*   row_start= (int*)(ws + off);   off += (size_t)(BN + 1) * 4;
    float* dinv     = (float*)(ws + off); off += (size_t)BN * 4;
    // rank (5.12 MB) + cnt/start2 (5.12 MB) alias B: B is first written by
    // agg1, stream-ordered after fill (the last reader of rank/start2).
    int*   rank     = (int*)Bb;
    int*   cnt      = (int*)Bb + (size_t)TOTE;

    const int ab = NB * (NN / 4);           // 20000

    k_count_lds<<<NPA, 256, 0, stream>>>(ei, rank, cnt);
    k_scan_g<<<NB, 1024, 0, stream>>>(cnt, row_start, dinv);
    // CSR fill (blocks 0..999, 5 edges/thread) + A = dinv*(x@W1^T+b1)
    k_fill_lin<<<FILLB + LINB, 256, 0, stream>>>(ei, rank, cnt, edge_col,
                                                 x, W1, b1, dinv, A);
    k_agg<<<ab, 256, 0, stream>>>(A, row_start, edge_col, dinv, Bb);   // B = h1
    k_linear<<<LINB, 256, 0, stream>>>(Bb, W2, b2, dinv, A);           // A = t2'
    k_agg<<<ab, 256, 0, stream>>>(A, row_start, edge_col, dinv, Bb);   // B = h2
    k_linear<<<LINB, 256, 0, stream>>>(Bb, W3, b3, dinv, A);           // A = t3'
    k_agg<<<ab, 256, 0, stream>>>(A, row_start, edge_col, dinv, out);  // out = h3
}